// Round 15
// baseline (134.893 us; speedup 1.0000x reference)
//
#include <hip/hip_runtime.h>
#include <hip/hip_bf16.h>

#define N_EDGES 312500
#define N_NODES 100000
#define D 256          // D_IN == D_HID == 256
#define BM 256         // edges per block: 8 tiles of 32, 8 waves (512 thr)
#define TILES (BM / 32)

typedef __attribute__((ext_vector_type(8)))  short bf16x8;
typedef __attribute__((ext_vector_type(16))) float f32x16;
typedef __attribute__((ext_vector_type(2)))  float f32x2;

static __device__ __forceinline__ unsigned short f2bf(float f) {
    union { float f; unsigned u; } c; c.f = f;
    unsigned r = c.u + 0x7fffu + ((c.u >> 16) & 1u);   // RNE
    return (unsigned short)(r >> 16);
}

// Pack W1 [256][256] f32 into bf16 MFMA fragment order:
// unit u = (nt*16 + kt)*64 + lane holds 8 bf16:
//   W1 row (nt*32 + (lane&31)), cols kt*16 + (lane>>5)*8 .. +7
__global__ void prep_w1(const float* __restrict__ W1, unsigned short* __restrict__ packed) {
    int t = blockIdx.x * blockDim.x + threadIdx.x;   // 0..8191
    if (t >= 8192) return;
    int lane = t & 63;
    int ktnt = t >> 6;
    int kt = ktnt & 15;
    int nt = ktnt >> 4;
    int r  = nt * 32 + (lane & 31);
    int c0 = kt * 16 + (lane >> 5) * 8;
    const float* src = W1 + r * D + c0;
    unsigned short v[8];
#pragma unroll
    for (int j = 0; j < 8; ++j) v[j] = f2bf(src[j]);
    uint4 u;
    u.x = (unsigned)v[0] | ((unsigned)v[1] << 16);
    u.y = (unsigned)v[2] | ((unsigned)v[3] << 16);
    u.z = (unsigned)v[4] | ((unsigned)v[5] << 16);
    u.w = (unsigned)v[6] | ((unsigned)v[7] << 16);
    reinterpret_cast<uint4*>(packed)[t] = u;
}

// Convert z [N_NODES*D] f32 -> bf16 (halves gather bytes)
__global__ void prep_z(const float* __restrict__ z, unsigned short* __restrict__ zb) {
    int t = blockIdx.x * blockDim.x + threadIdx.x;
    if (t >= (N_NODES * D) / 8) return;
    const float4* src = reinterpret_cast<const float4*>(z) + 2 * (size_t)t;
    float4 v0 = src[0], v1 = src[1];
    uint4 u;
    u.x = (unsigned)f2bf(v0.x) | ((unsigned)f2bf(v0.y) << 16);
    u.y = (unsigned)f2bf(v0.z) | ((unsigned)f2bf(v0.w) << 16);
    u.z = (unsigned)f2bf(v1.x) | ((unsigned)f2bf(v1.y) << 16);
    u.w = (unsigned)f2bf(v1.z) | ((unsigned)f2bf(v1.w) << 16);
    reinterpret_cast<uint4*>(zb)[t] = u;
}

// W1-stationary edge decoder, async-split gather (r12/r14 structure):
//   D[h][e] = mfma(A = W1 frags in regs, B = edge-product frags from LDS).
// LDS tile buffer: [kt 0..15][unit 0..63][16B], unit = (m + 32*kh) ^ (kt&7).
// lidx holds PRE-SCALED byte offsets (node_index * 512) into bf16 zb.
template<bool ZB>
__global__ __launch_bounds__(512, 4) void edge_decoder(
    const float* __restrict__ z,
    const unsigned short* __restrict__ zb,
    const int* __restrict__ edge,
    const unsigned short* __restrict__ w1p,
    const float* __restrict__ b1,
    const float* __restrict__ W2,
    const float* __restrict__ b2,
    float* __restrict__ out)
{
    __shared__ unsigned char ldsT[2][16 * 64 * 16];     // 2 x 16 KiB tile dbuf
    __shared__ float  sbufp[TILES][8][32];              // per-tile per-wave partials
    __shared__ float  epb[8][2][16];                    // b1 per (wave,kh,r)
    __shared__ float  epw[8][2][16];                    // W2 per (wave,kh,r)
    __shared__ int    lidx[2][BM];                      // byte offsets (i * 512)

    const int tid  = threadIdx.x;
    const int lane = tid & 63;
    const int w    = tid >> 6;          // 0..7 = this wave's nt (h-rows 32w..32w+31)
    const int blockBase = blockIdx.x * BM;

    // gather-phase lane mapping: lane owns dims 4*lane..4*lane+3
    const int gkt  = lane >> 2;
    const int gkh  = (lane >> 1) & 1;
    const int ghal = lane & 1;
    const int d0   = 4 * lane;
    const int gktx = gkt & 7;

    // per-thread base pointers for the gather (hoisted lane offset)
    const unsigned char* zbd = reinterpret_cast<const unsigned char*>(zb) + (d0 << 1);
    const unsigned char* zfd = reinterpret_cast<const unsigned char*>(z)  + (d0 << 2);

    // ---- prologue: W1 A-frags (stationary), idx table, epi tables ----
    bf16x8 a[16];
    {
        const bf16x8* bp = reinterpret_cast<const bf16x8*>(w1p);
#pragma unroll
        for (int kt = 0; kt < 16; ++kt)
            a[kt] = bp[(w * 16 + kt) * 64 + lane];
    }
    {
        int e = blockBase + (tid & 255);
        if (e >= N_EDGES) e = N_EDGES - 1;              // clamp tail
        int half = tid >> 8;                            // 0: src, 1: dst
        lidx[half][tid & 255] = edge[half * N_EDGES + e] << 9;   // i * 512 bytes
    }
    if (tid < 256) {
        int w_  = tid >> 5;
        int kh_ = (tid >> 4) & 1;
        int r_  = tid & 15;
        int h   = w_ * 32 + (r_ & 3) + 8 * (r_ >> 2) + 4 * kh_;
        epb[w_][kh_][r_] = b1[h];
        epw[w_][kh_][r_] = W2[h];
    }
    __syncthreads();                                    // lidx/epi visible

    // ---- async-split staging (ZB path): issue loads early, commit late ----
    uint2 P[4], Q[4];                                   // 16 VGPRs in flight
    auto issue = [&](int t) {
#pragma unroll
        for (int j = 0; j < 4; ++j) {
            int el = t * 32 + w * 4 + j;
            P[j] = *reinterpret_cast<const uint2*>(zbd + (unsigned)lidx[0][el]);
            Q[j] = *reinterpret_cast<const uint2*>(zbd + (unsigned)lidx[1][el]);
        }
    };
    auto commit = [&](int b) {
        unsigned char* tb = ldsT[b] + (gkt << 10);
#pragma unroll
        for (int j = 0; j < 4; ++j) {
            __hip_bfloat162 h0 = __hmul2(*reinterpret_cast<const __hip_bfloat162*>(&P[j].x),
                                         *reinterpret_cast<const __hip_bfloat162*>(&Q[j].x));
            __hip_bfloat162 h1 = __hmul2(*reinterpret_cast<const __hip_bfloat162*>(&P[j].y),
                                         *reinterpret_cast<const __hip_bfloat162*>(&Q[j].y));
            int m = w * 4 + j;
            int unit = (m + (gkh << 5)) ^ gktx;
            *reinterpret_cast<uint2*>(tb + unit * 16 + ghal * 8) =
                make_uint2(*reinterpret_cast<unsigned*>(&h0),
                           *reinterpret_cast<unsigned*>(&h1));
        }
    };
    // fallback serial stage (f32 z, no workspace): byte off = lidx*2 (f32 rows)
    auto stage_serial = [&](int t, int b) {
        unsigned char* tb = ldsT[b] + (gkt << 10);
#pragma unroll
        for (int j = 0; j < 4; ++j) {
            int el = t * 32 + w * 4 + j;
            size_t o0 = (size_t)(unsigned)lidx[0][el] * 2;
            size_t o1 = (size_t)(unsigned)lidx[1][el] * 2;
            float4 p = *reinterpret_cast<const float4*>(zfd + o0);
            float4 q = *reinterpret_cast<const float4*>(zfd + o1);
            __hip_bfloat162 h0 = __float22bfloat162_rn(make_float2(p.x * q.x, p.y * q.y));
            __hip_bfloat162 h1 = __float22bfloat162_rn(make_float2(p.z * q.z, p.w * q.w));
            int m = w * 4 + j;
            int unit = (m + (gkh << 5)) ^ gktx;
            *reinterpret_cast<uint2*>(tb + unit * 16 + ghal * 8) =
                make_uint2(*reinterpret_cast<unsigned*>(&h0),
                           *reinterpret_cast<unsigned*>(&h1));
        }
    };

    if constexpr (ZB) { issue(0); commit(0); }
    else              { stage_serial(0, 0); }
    __syncthreads();                                    // tile 0 visible

    const int kh = lane >> 5;

    // ---- main loop: issue(t+1) -> compute(t) -> commit(t+1) -> barrier ----
#pragma unroll 1
    for (int t = 0; t < TILES; ++t) {
        if constexpr (ZB) { if (t + 1 < TILES) issue(t + 1); }

        const unsigned char* tb = ldsT[t & 1];
        f32x16 acc;
#pragma unroll
        for (int i = 0; i < 16; ++i) acc[i] = 0.f;
        __builtin_amdgcn_s_setprio(1);
#pragma unroll
        for (int kt = 0; kt < 16; ++kt) {
            bf16x8 bfrag = *reinterpret_cast<const bf16x8*>(
                tb + (kt << 10) + ((lane ^ (kt & 7)) << 4));
            acc = __builtin_amdgcn_mfma_f32_32x32x16_bf16(a[kt], bfrag, acc, 0, 0, 0);
        }
        __builtin_amdgcn_s_setprio(0);

        // epilogue: bias + branchless ELU + W2 dot, f32x2-packed
        // elu(h) = max(h,0) + (exp(min(h,0)) - 1)   (exact for both signs)
        float s = 0.f;
#pragma unroll
        for (int r = 0; r < 16; r += 2) {
            f32x2 accp; accp[0] = acc[r]; accp[1] = acc[r + 1];
            f32x2 b1p = *reinterpret_cast<const f32x2*>(&epb[w][kh][r]);
            f32x2 w2p = *reinterpret_cast<const f32x2*>(&epw[w][kh][r]);
            f32x2 h = accp + b1p;
            f32x2 hmax; hmax[0] = fmaxf(h[0], 0.f); hmax[1] = fmaxf(h[1], 0.f);
            f32x2 hmin; hmin[0] = fminf(h[0], 0.f); hmin[1] = fminf(h[1], 0.f);
            f32x2 em1;  em1[0] = __expf(hmin[0]) - 1.f; em1[1] = __expf(hmin[1]) - 1.f;
            f32x2 v = hmax + em1;
            s += v[0] * w2p[0] + v[1] * w2p[1];
        }
        s += __shfl_xor(s, 32);                 // combine the two kh halves
        if (lane < 32) sbufp[t][w][lane] = s;

        if constexpr (ZB) { if (t + 1 < TILES) commit((t + 1) & 1); }
        else              { if (t + 1 < TILES) stage_serial(t + 1, (t + 1) & 1); }

        __syncthreads();                        // tile t+1 + partials visible
    }

    // ---- final: sum the 8 nt-partials per edge and write ----
    if (tid < BM) {
        int t  = tid >> 5;
        int e  = tid & 31;
        float sum = b2[0];
#pragma unroll
        for (int ww = 0; ww < 8; ++ww) sum += sbufp[t][ww][e];
        int eo = blockBase + tid;
        if (eo < N_EDGES) out[eo] = sum;
    }
}

extern "C" void kernel_launch(void* const* d_in, const int* in_sizes, int n_in,
                              void* d_out, int out_size, void* d_ws, size_t ws_size,
                              hipStream_t stream) {
    const float* z    = (const float*)d_in[0];
    const int*   edge = (const int*)d_in[1];
    const float* W1   = (const float*)d_in[2];
    const float* b1   = (const float*)d_in[3];
    const float* W2   = (const float*)d_in[4];
    const float* b2   = (const float*)d_in[5];
    float*       out  = (float*)d_out;

    unsigned short* w1p = (unsigned short*)d_ws;              // 128 KiB packed bf16 W1
    const size_t zbOff  = 131072;
    const size_t zbNeed = zbOff + (size_t)N_NODES * D * 2;    // + 51.2 MB bf16 z

    prep_w1<<<32, 256, 0, stream>>>(W1, w1p);

    int blocks = (N_EDGES + BM - 1) / BM;
    if (ws_size >= zbNeed) {
        unsigned short* zb = (unsigned short*)((char*)d_ws + zbOff);
        prep_z<<<(N_NODES * D / 8 + 255) / 256, 256, 0, stream>>>(z, zb);
        edge_decoder<true><<<blocks, 512, 0, stream>>>(z, zb, edge, w1p, b1, W2, b2, out);
    } else {
        edge_decoder<false><<<blocks, 512, 0, stream>>>(z, nullptr, edge, w1p, b1, W2, b2, out);
    }
}

// Round 16
// 92.491 us; speedup vs baseline: 1.4584x; 1.4584x over previous
//
#include <hip/hip_runtime.h>
#include <hip/hip_bf16.h>

#define N_EDGES 312500
#define N_NODES 100000
#define D 256          // D_IN == D_HID == 256
#define BM 256         // edges per block: 8 tiles of 32, 8 waves (512 thr)
#define TILES (BM / 32)

typedef __attribute__((ext_vector_type(8)))  short bf16x8;
typedef __attribute__((ext_vector_type(16))) float f32x16;

static __device__ __forceinline__ unsigned short f2bf(float f) {
    union { float f; unsigned u; } c; c.f = f;
    unsigned r = c.u + 0x7fffu + ((c.u >> 16) & 1u);   // RNE
    return (unsigned short)(r >> 16);
}

// Pack W1 [256][256] f32 into bf16 MFMA fragment order:
// unit u = (nt*16 + kt)*64 + lane holds 8 bf16:
//   W1 row (nt*32 + (lane&31)), cols kt*16 + (lane>>5)*8 .. +7
__global__ void prep_w1(const float* __restrict__ W1, unsigned short* __restrict__ packed) {
    int t = blockIdx.x * blockDim.x + threadIdx.x;   // 0..8191
    if (t >= 8192) return;
    int lane = t & 63;
    int ktnt = t >> 6;
    int kt = ktnt & 15;
    int nt = ktnt >> 4;
    int r  = nt * 32 + (lane & 31);
    int c0 = kt * 16 + (lane >> 5) * 8;
    const float* src = W1 + r * D + c0;
    unsigned short v[8];
#pragma unroll
    for (int j = 0; j < 8; ++j) v[j] = f2bf(src[j]);
    uint4 u;
    u.x = (unsigned)v[0] | ((unsigned)v[1] << 16);
    u.y = (unsigned)v[2] | ((unsigned)v[3] << 16);
    u.z = (unsigned)v[4] | ((unsigned)v[5] << 16);
    u.w = (unsigned)v[6] | ((unsigned)v[7] << 16);
    reinterpret_cast<uint4*>(packed)[t] = u;
}

// Convert z [N_NODES*D] f32 -> bf16 (halves gather bytes)
__global__ void prep_z(const float* __restrict__ z, unsigned short* __restrict__ zb) {
    int t = blockIdx.x * blockDim.x + threadIdx.x;
    if (t >= (N_NODES * D) / 8) return;
    const float4* src = reinterpret_cast<const float4*>(z) + 2 * (size_t)t;
    float4 v0 = src[0], v1 = src[1];
    uint4 u;
    u.x = (unsigned)f2bf(v0.x) | ((unsigned)f2bf(v0.y) << 16);
    u.y = (unsigned)f2bf(v0.z) | ((unsigned)f2bf(v0.w) << 16);
    u.z = (unsigned)f2bf(v1.x) | ((unsigned)f2bf(v1.y) << 16);
    u.w = (unsigned)f2bf(v1.z) | ((unsigned)f2bf(v1.w) << 16);
    reinterpret_cast<uint4*>(zb)[t] = u;
}

// W1-stationary edge decoder, async-split gather (r12/r14 structure):
//   D[h][e] = mfma(A = W1 frags in regs, B = edge-product frags from LDS).
// LDS tile buffer: [kt 0..15][unit 0..63][16B], unit = (m + 32*kh) ^ (kt&7).
// lidx holds PRE-SCALED byte offsets (node_index * 512) into bf16 zb.
template<bool ZB>
__global__ __launch_bounds__(512, 4) void edge_decoder(
    const float* __restrict__ z,
    const unsigned short* __restrict__ zb,
    const int* __restrict__ edge,
    const unsigned short* __restrict__ w1p,
    const float* __restrict__ b1,
    const float* __restrict__ W2,
    const float* __restrict__ b2,
    float* __restrict__ out)
{
    __shared__ unsigned char ldsT[2][16 * 64 * 16];     // 2 x 16 KiB tile dbuf
    __shared__ float  sbufp[TILES][8][32];              // per-tile per-wave partials
    __shared__ float2 epi[8][2][16];                    // {b1,W2} per (wave,kh,r)
    __shared__ int    lidx[2][BM];                      // byte offsets (i * 512)

    const int tid  = threadIdx.x;
    const int lane = tid & 63;
    const int w    = tid >> 6;          // 0..7 = this wave's nt (h-rows 32w..32w+31)
    const int blockBase = blockIdx.x * BM;

    // gather-phase lane mapping: lane owns dims 4*lane..4*lane+3
    const int gkt  = lane >> 2;
    const int gkh  = (lane >> 1) & 1;
    const int ghal = lane & 1;
    const int d0   = 4 * lane;
    const int gktx = gkt & 7;

    // per-thread base pointers for the gather (hoisted lane offset)
    const unsigned char* zbd = reinterpret_cast<const unsigned char*>(zb) + (d0 << 1);
    const unsigned char* zfd = reinterpret_cast<const unsigned char*>(z)  + (d0 << 2);

    // ---- prologue: W1 A-frags (stationary), idx table, epi table ----
    bf16x8 a[16];
    {
        const bf16x8* bp = reinterpret_cast<const bf16x8*>(w1p);
#pragma unroll
        for (int kt = 0; kt < 16; ++kt)
            a[kt] = bp[(w * 16 + kt) * 64 + lane];
    }
    {
        int e = blockBase + (tid & 255);
        if (e >= N_EDGES) e = N_EDGES - 1;              // clamp tail
        int half = tid >> 8;                            // 0: src, 1: dst
        lidx[half][tid & 255] = edge[half * N_EDGES + e] << 9;   // i * 512 bytes
    }
    if (tid < 256) {
        int w_  = tid >> 5;
        int kh_ = (tid >> 4) & 1;
        int r_  = tid & 15;
        int h   = w_ * 32 + (r_ & 3) + 8 * (r_ >> 2) + 4 * kh_;
        epi[w_][kh_][r_] = make_float2(b1[h], W2[h]);
    }
    __syncthreads();                                    // lidx/epi visible

    // ---- async-split staging (ZB path): issue loads early, commit late ----
    uint2 P[4], Q[4];                                   // 16 VGPRs in flight
    auto issue = [&](int t) {
#pragma unroll
        for (int j = 0; j < 4; ++j) {
            int el = t * 32 + w * 4 + j;
            P[j] = *reinterpret_cast<const uint2*>(zbd + (unsigned)lidx[0][el]);
            Q[j] = *reinterpret_cast<const uint2*>(zbd + (unsigned)lidx[1][el]);
        }
    };
    auto commit = [&](int b) {
        unsigned char* tb = ldsT[b] + (gkt << 10);
#pragma unroll
        for (int j = 0; j < 4; ++j) {
            __hip_bfloat162 h0 = __hmul2(*reinterpret_cast<const __hip_bfloat162*>(&P[j].x),
                                         *reinterpret_cast<const __hip_bfloat162*>(&Q[j].x));
            __hip_bfloat162 h1 = __hmul2(*reinterpret_cast<const __hip_bfloat162*>(&P[j].y),
                                         *reinterpret_cast<const __hip_bfloat162*>(&Q[j].y));
            int m = w * 4 + j;
            int unit = (m + (gkh << 5)) ^ gktx;
            *reinterpret_cast<uint2*>(tb + unit * 16 + ghal * 8) =
                make_uint2(*reinterpret_cast<unsigned*>(&h0),
                           *reinterpret_cast<unsigned*>(&h1));
        }
    };
    // fallback serial stage (f32 z, no workspace): byte off = lidx*2 (f32 rows)
    auto stage_serial = [&](int t, int b) {
        unsigned char* tb = ldsT[b] + (gkt << 10);
#pragma unroll
        for (int j = 0; j < 4; ++j) {
            int el = t * 32 + w * 4 + j;
            size_t o0 = (size_t)(unsigned)lidx[0][el] * 2;
            size_t o1 = (size_t)(unsigned)lidx[1][el] * 2;
            float4 p = *reinterpret_cast<const float4*>(zfd + o0);
            float4 q = *reinterpret_cast<const float4*>(zfd + o1);
            __hip_bfloat162 h0 = __float22bfloat162_rn(make_float2(p.x * q.x, p.y * q.y));
            __hip_bfloat162 h1 = __float22bfloat162_rn(make_float2(p.z * q.z, p.w * q.w));
            int m = w * 4 + j;
            int unit = (m + (gkh << 5)) ^ gktx;
            *reinterpret_cast<uint2*>(tb + unit * 16 + ghal * 8) =
                make_uint2(*reinterpret_cast<unsigned*>(&h0),
                           *reinterpret_cast<unsigned*>(&h1));
        }
    };

    if constexpr (ZB) { issue(0); commit(0); }
    else              { stage_serial(0, 0); }
    __syncthreads();                                    // tile 0 visible

    const int kh = lane >> 5;

    // ---- main loop: issue(t+1) -> compute(t) -> commit(t+1) -> barrier ----
#pragma unroll 1
    for (int t = 0; t < TILES; ++t) {
        if constexpr (ZB) { if (t + 1 < TILES) issue(t + 1); }

        const unsigned char* tb = ldsT[t & 1];
        f32x16 acc;
#pragma unroll
        for (int i = 0; i < 16; ++i) acc[i] = 0.f;
        __builtin_amdgcn_s_setprio(1);
#pragma unroll
        for (int kt = 0; kt < 16; ++kt) {
            bf16x8 bfrag = *reinterpret_cast<const bf16x8*>(
                tb + (kt << 10) + ((lane ^ (kt & 7)) << 4));
            acc = __builtin_amdgcn_mfma_f32_32x32x16_bf16(a[kt], bfrag, acc, 0, 0, 0);
        }
        __builtin_amdgcn_s_setprio(0);

        // epilogue: bias + ELU + W2 dot over this wave's 16 h-rows
        float s = 0.f;
#pragma unroll
        for (int r = 0; r < 16; ++r) {
            float2 bw = epi[w][kh][r];
            float h = acc[r] + bw.x;
            s += (h > 0.f ? h : (__expf(h) - 1.0f)) * bw.y;
        }
        s += __shfl_xor(s, 32);                 // combine the two kh halves
        if (lane < 32) sbufp[t][w][lane] = s;

        if constexpr (ZB) { if (t + 1 < TILES) commit((t + 1) & 1); }
        else              { if (t + 1 < TILES) stage_serial(t + 1, (t + 1) & 1); }

        __syncthreads();                        // tile t+1 + partials visible
    }

    // ---- final: sum the 8 nt-partials per edge and write ----
    if (tid < BM) {
        int t  = tid >> 5;
        int e  = tid & 31;
        float sum = b2[0];
#pragma unroll
        for (int ww = 0; ww < 8; ++ww) sum += sbufp[t][ww][e];
        int eo = blockBase + tid;
        if (eo < N_EDGES) out[eo] = sum;
    }
}

extern "C" void kernel_launch(void* const* d_in, const int* in_sizes, int n_in,
                              void* d_out, int out_size, void* d_ws, size_t ws_size,
                              hipStream_t stream) {
    const float* z    = (const float*)d_in[0];
    const int*   edge = (const int*)d_in[1];
    const float* W1   = (const float*)d_in[2];
    const float* b1   = (const float*)d_in[3];
    const float* W2   = (const float*)d_in[4];
    const float* b2   = (const float*)d_in[5];
    float*       out  = (float*)d_out;

    unsigned short* w1p = (unsigned short*)d_ws;              // 128 KiB packed bf16 W1
    const size_t zbOff  = 131072;
    const size_t zbNeed = zbOff + (size_t)N_NODES * D * 2;    // + 51.2 MB bf16 z

    prep_w1<<<32, 256, 0, stream>>>(W1, w1p);

    int blocks = (N_EDGES + BM - 1) / BM;
    if (ws_size >= zbNeed) {
        unsigned short* zb = (unsigned short*)((char*)d_ws + zbOff);
        prep_z<<<(N_NODES * D / 8 + 255) / 256, 256, 0, stream>>>(z, zb);
        edge_decoder<true><<<blocks, 512, 0, stream>>>(z, zb, edge, w1p, b1, W2, b2, out);
    } else {
        edge_decoder<false><<<blocks, 512, 0, stream>>>(z, nullptr, edge, w1p, b1, W2, b2, out);
    }
}